// Round 1
// baseline (255.215 us; speedup 1.0000x reference)
//
#include <hip/hip_runtime.h>

#define NPTS 65536
#define BATCH 2
#define CCH 128
#define HIDC 64
#define LDB 520      // k_zr bext row stride u16 (512+8 pad)
#define LDB2 264     // k_q bext row stride u16 (256+8 pad)
#define PLD 130      // k_pack tile row stride u16 (2 mod 4 -> 2-way banks on transpose writes)

typedef unsigned short u16;
typedef unsigned int u32;
typedef __bf16 bf16_t;
typedef bf16_t bf16x8 __attribute__((ext_vector_type(8)));
typedef float f32x4 __attribute__((ext_vector_type(4)));
typedef float f32x2 __attribute__((ext_vector_type(2)));

__device__ __forceinline__ u16 f2bf(float f){
  union { float f; unsigned u; } v; v.f = f;
  unsigned r = v.u + 0x7FFFu + ((v.u >> 16) & 1u);
  return (u16)(r >> 16);
}
__device__ __forceinline__ float bf2f(u16 u){
  union { unsigned u; float f; } v; v.u = ((unsigned)u) << 16; return v.f;
}
__device__ __forceinline__ u32 pkrn(float a, float b){
  union { float f; u32 u; } ua, ub; ua.f = a; ub.f = b;
  return ((ua.u + 0x8000u) >> 16) | ((ub.u + 0x8000u) & 0xffff0000u);
}
__device__ __forceinline__ float sigmoidf_(float v){ return 1.f/(1.f+__expf(-v)); }
__device__ __forceinline__ float tanhf_(float v){
  v = fminf(10.f, fmaxf(-10.f, v));
  float e = __expf(2.f*v);
  return (e-1.f)/(e+1.f);
}

// A matrices (bf16), fragment-permuted. First 98304: Az|Ar|Aq at K=512
// (phys k = s*32+quad*8+t; j=pk>>7, chunk=(pk>>3)&15, tt=pk&7;
//  orig=chunk*32+j*8+tt; c=orig>>2, m=orig&3). Then 16384: Aqrh at K=256
// (k2=s*32+quad*8+t; j=k2>>6, chunk=(k2>>3)&7; c in [0,64)).
__global__ __launch_bounds__(256) void kprep(
    const float* __restrict__ wz, const float* __restrict__ wzp, const float* __restrict__ bzp,
    const float* __restrict__ wr, const float* __restrict__ wrp, const float* __restrict__ brp,
    const float* __restrict__ wq, const float* __restrict__ wqp, const float* __restrict__ bqp,
    u16* __restrict__ A){
  int idx = blockIdx.x*256 + threadIdx.x;          // 0..114687
  if (idx < 98304){
    int t = idx & 7, o = (idx>>3)&63, quad = (idx>>9)&3, s = (idx>>11)&15, g = idx>>15;
    int pk = s*32 + quad*8 + t;
    int j = pk>>7, chunk = (pk>>3)&15, tt = pk&7;
    int orig = chunk*32 + j*8 + tt;
    int c = orig>>2, m = orig&3;
    const float* W  = (g==0)? wz  : (g==1)? wr  : wq;
    const float* wp = (g==0)? wzp : (g==1)? wrp : wqp;
    const float* bp = (g==0)? bzp : (g==1)? brp : bqp;
    float coef = m ? wp[c*3 + m - 1] : bp[c];
    A[idx] = f2bf(W[o*CCH + c] * coef);
  } else {
    int i2 = idx - 98304;
    int t = i2 & 7, o = (i2>>3)&63, quad = (i2>>9)&3, s = (i2>>11)&7;
    int k2 = s*32 + quad*8 + t;
    int j = k2>>6, chunk = (k2>>3)&7, tt = k2&7;
    int orig = chunk*32 + j*8 + tt;
    int c = orig>>2, m = orig&3;                   // c in [0,64): rh channels
    float coef = m ? wqp[c*3 + m - 1] : bqp[c];
    A[idx] = f2bf(wq[o*CCH + c] * coef);
  }
}

// Transpose h,x [B,64,N] fp32 -> hxT [B,N,128] bf16 rows.
__global__ __launch_bounds__(256) void k_pack(const float* __restrict__ h,
    const float* __restrict__ x, u16* __restrict__ hxT){
  __shared__ __align__(16) u16 tile[64*PLD];
  int tid = threadIdx.x;
  int b = blockIdx.x >> 10, n0 = (blockIdx.x & 1023) << 6;
  #pragma unroll
  for (int i = 0; i < 8; ++i){
    int cc = (tid>>4) + i*16;                      // 0..127
    int nn = (tid & 15)*4;
    const float* src = (cc < HIDC)
        ? (h + (((size_t)(b*HIDC + cc))<<16) + n0 + nn)
        : (x + (((size_t)(b*HIDC + cc - HIDC))<<16) + n0 + nn);
    float4 v = *(const float4*)src;
    tile[(nn+0)*PLD + cc] = f2bf(v.x);
    tile[(nn+1)*PLD + cc] = f2bf(v.y);
    tile[(nn+2)*PLD + cc] = f2bf(v.z);
    tile[(nn+3)*PLD + cc] = f2bf(v.w);
  }
  __syncthreads();
  #pragma unroll
  for (int i = 0; i < 4; ++i){
    int tsk = tid + (i<<8);                        // 0..1023: 64 n x 16 chunks
    int n = tsk>>4, ch = (tsk&15)*8;
    uint4 v = *(const uint4*)(tile + n*PLD + ch);
    *(uint4*)(hxT + (((size_t)(b<<16) + n0 + n)<<7) + ch) = v;
  }
}

// Moment accumulation on f32x2 so LLVM can select v_pk_fma_f32 / v_pk_add_f32.
// m-arrays: index q_ = dword (channel pair); .x = even channel, .y = odd channel.
#define ACCUM(gv, rv) { \
  u32 dw_[4] = {gv.x, gv.y, gv.z, gv.w}; \
  _Pragma("unroll") \
  for (int q_ = 0; q_ < 4; ++q_){ \
    union { u32 u; float f; } lo_, hi_; \
    lo_.u = dw_[q_] << 16; hi_.u = dw_[q_] & 0xffff0000u; \
    f32x2 v_ = {lo_.f, hi_.f}; \
    m0[q_] += v_; mx[q_] += rv.x * v_; my[q_] += rv.y * v_; mz[q_] += rv.z * v_; \
  } }

#define PACKROW(row, CHOFF, STRIDE) { \
  _Pragma("unroll") \
  for (int j_ = 0; j_ < 4; ++j_){ \
    uint4 v_; \
    v_.x = pkrn(m0[j_].x, mx[j_].x); v_.y = pkrn(my[j_].x, mz[j_].x); \
    v_.z = pkrn(m0[j_].y, mx[j_].y); v_.w = pkrn(my[j_].y, mz[j_].y); \
    *(uint4*)((row) + j_*(STRIDE) + (CHOFF)) = v_; \
  } }

// z & r gates + q-gate x-partial. 16 points/block (LDS 17920 B -> 8 blocks/CU).
__global__ __launch_bounds__(256, 8) void k_zr(
    const float* __restrict__ xyz, const float* __restrict__ h,
    const int* __restrict__ knn,
    const float* __restrict__ bz_out, const float* __restrict__ br_out,
    const u16* __restrict__ Azr,    // Az at 0, Ar at +32768, Aq at +65536
    const u16* __restrict__ hxT, u16* __restrict__ rhT,
    u16* __restrict__ z_ws, u16* __restrict__ qx_ws)
{
  __shared__ __align__(16) u16 bext[16*LDB];       // 16640 B
  __shared__ __align__(16) float4 relk[64];
  __shared__ __align__(16) int4 jlds[16];

  int tid = threadIdx.x; int lane = tid & 63; int wv = tid >> 6;
  int b = blockIdx.x >> 12, n0 = (blockIdx.x & 4095) << 4;
  size_t bN = (size_t)b * NPTS;

  if (tid < 64){
    int p = tid >> 2, k = tid & 3;
    int j = knn[((bN + n0 + p) << 2) + k];
    ((int*)jlds)[tid] = j;
    const float* xb = xyz + (size_t)b*3*NPTS;
    float cx = xb[n0+p], cy = xb[NPTS + n0+p], cz = xb[2*NPTS + n0+p];
    relk[tid] = make_float4(xb[j]-cx, xb[NPTS+j]-cy, xb[2*NPTS+j]-cz, 0.f);
  }
  __syncthreads();

  // gather: 1 task/thread (16 p x 16 chunks), all 4 loads issued up front
  const u16* hxTb = hxT + (bN << 7);
  int pA = tid >> 4, chk = tid & 15;
  int4 jA = jlds[pA];
  const u16* cb = hxTb + chk*8;
  uint4 ga0 = *(const uint4*)(cb + (((size_t)jA.x)<<7));
  uint4 ga1 = *(const uint4*)(cb + (((size_t)jA.y)<<7));
  uint4 ga2 = *(const uint4*)(cb + (((size_t)jA.z)<<7));
  uint4 ga3 = *(const uint4*)(cb + (((size_t)jA.w)<<7));
  {
    float4 r0 = relk[pA*4+0], r1 = relk[pA*4+1], r2 = relk[pA*4+2], r3 = relk[pA*4+3];
    f32x2 m0[4] = {{0,0},{0,0},{0,0},{0,0}}, mx[4] = {{0,0},{0,0},{0,0},{0,0}};
    f32x2 my[4] = {{0,0},{0,0},{0,0},{0,0}}, mz[4] = {{0,0},{0,0},{0,0},{0,0}};
    ACCUM(ga0, r0); ACCUM(ga1, r1); ACCUM(ga2, r2); ACCUM(ga3, r3);
    PACKROW(bext + pA*LDB, chk*8, 128);
  }
  __syncthreads();

  // MFMA: z,r over K=512; q x-part over the s&2 slices (c>=64). Single n-tile (16 pts).
  int l15 = lane & 15, quad = lane >> 4;
  int orow = wv*16 + l15;
  f32x4 accz = (f32x4){0,0,0,0}, accr = (f32x4){0,0,0,0}, accq = (f32x4){0,0,0,0};
  #pragma unroll
  for (int s = 0; s < 16; ++s){
    bf16x8 az = *(const bf16x8*)(Azr + ((s*4 + quad)*64 + orow)*8);
    bf16x8 ar = *(const bf16x8*)(Azr + 32768 + ((s*4 + quad)*64 + orow)*8);
    bf16x8 bb = *(const bf16x8*)(bext + l15*LDB + s*32 + quad*8);
    accz = __builtin_amdgcn_mfma_f32_16x16x32_bf16(az, bb, accz, 0, 0, 0);
    accr = __builtin_amdgcn_mfma_f32_16x16x32_bf16(ar, bb, accr, 0, 0, 0);
    if (s & 2){
      bf16x8 aq = *(const bf16x8*)(Azr + 65536 + ((s*4 + quad)*64 + orow)*8);
      accq = __builtin_amdgcn_mfma_f32_16x16x32_bf16(aq, bb, accq, 0, 0, 0);
    }
  }
  __syncthreads();   // bext reads done; reuse as staging

  u16* zst  = bext;                 // [64 o][24]
  u16* rhst = bext + 1536;          // [16 p][72]
  u16* qxst = bext + 2688;          // [64 o][24]
  #pragma unroll
  for (int reg = 0; reg < 4; ++reg){
    int o = wv*16 + quad*4 + reg;               // C/D: row = quad*4+reg
    int p = l15;                                // col = lane&15
    float zf = sigmoidf_(accz[reg] + bz_out[o]);
    float rf = sigmoidf_(accr[reg] + br_out[o]);
    float hv = h[(((size_t)(b*HIDC + o))<<16) + n0 + p];
    zst[o*24 + p] = f2bf(zf);
    rhst[p*72 + o] = f2bf(rf * hv);
    qxst[o*24 + p] = f2bf(accq[reg]);           // no bias (bq_out added in k_q)
  }
  __syncthreads();

  if (tid < 128){ // rhT: 16 p x 8 ch-chunks = 128 uint4
    int p = tid >> 3, ch = (tid & 7)*8;
    uint4 v = *(const uint4*)(rhst + p*72 + ch);
    *(uint4*)(rhT + ((bN + n0 + p)<<6) + ch) = v;
  }
  { // z & qx: 64 o x 2 halves x 2 arrays = 256 uint4, one per thread
    int o = tid >> 2, hl = (tid >> 1) & 1, pc = (tid & 1)*8;
    const u16* src = hl ? qxst : zst;
    u16* dst = hl ? qx_ws : z_ws;
    uint4 v = *(const uint4*)(src + o*24 + pc);
    *(uint4*)(dst + (((size_t)(b*HIDC + o))<<16) + n0 + pc) = v;
  }
}

// q gate (rh half via gather, x half from qx_ws) + final combine.
// 32 points/block (LDS 19456 B -> 8 blocks/CU).
__global__ __launch_bounds__(256, 8) void k_q(
    const float* __restrict__ xyz, const float* __restrict__ h,
    const int* __restrict__ knn,
    const float* __restrict__ bq_out,
    const u16* __restrict__ Aqrh,
    const u16* __restrict__ rhT, const u16* __restrict__ z_ws,
    const u16* __restrict__ qx_ws, float* __restrict__ out)
{
  __shared__ __align__(16) u16 bext[32*LDB2];      // 16896 B
  __shared__ __align__(16) float4 relk[128];
  __shared__ __align__(16) int4 jlds[32];

  int tid = threadIdx.x; int lane = tid & 63; int wv = tid >> 6;
  int b = blockIdx.x >> 11, n0 = (blockIdx.x & 2047) << 5;
  size_t bN = (size_t)b * NPTS;

  if (tid < 128){
    int p = tid >> 2, k = tid & 3;
    int j = knn[((bN + n0 + p) << 2) + k];
    ((int*)jlds)[tid] = j;
    const float* xb = xyz + (size_t)b*3*NPTS;
    float cx = xb[n0+p], cy = xb[NPTS + n0+p], cz = xb[2*NPTS + n0+p];
    relk[tid] = make_float4(xb[j]-cx, xb[NPTS+j]-cy, xb[2*NPTS+j]-cz, 0.f);
  }
  __syncthreads();

  // gather rh rows (64 ch = 128 B): 1 task/thread, 4 loads in flight
  const u16* rhTb = rhT + (bN << 6);
  int pA = tid >> 3, chk = tid & 7;
  int4 jA = jlds[pA];
  const u16* cb = rhTb + chk*8;
  uint4 ga0 = *(const uint4*)(cb + (((size_t)jA.x)<<6));
  uint4 ga1 = *(const uint4*)(cb + (((size_t)jA.y)<<6));
  uint4 ga2 = *(const uint4*)(cb + (((size_t)jA.z)<<6));
  uint4 ga3 = *(const uint4*)(cb + (((size_t)jA.w)<<6));
  {
    float4 r0 = relk[pA*4+0], r1 = relk[pA*4+1], r2 = relk[pA*4+2], r3 = relk[pA*4+3];
    f32x2 m0[4] = {{0,0},{0,0},{0,0},{0,0}}, mx[4] = {{0,0},{0,0},{0,0},{0,0}};
    f32x2 my[4] = {{0,0},{0,0},{0,0},{0,0}}, mz[4] = {{0,0},{0,0},{0,0},{0,0}};
    ACCUM(ga0, r0); ACCUM(ga1, r1); ACCUM(ga2, r2); ACCUM(ga3, r3);
    PACKROW(bext + pA*LDB2, chk*8, 64);
  }
  __syncthreads();

  int l15 = lane & 15, quad = lane >> 4;
  int orow = wv*16 + l15;
  f32x4 acc[2];
  #pragma unroll
  for (int nt = 0; nt < 2; ++nt) acc[nt] = (f32x4){0,0,0,0};
  #pragma unroll
  for (int s = 0; s < 8; ++s){
    bf16x8 aq = *(const bf16x8*)(Aqrh + ((s*4 + quad)*64 + orow)*8);
    #pragma unroll
    for (int nt = 0; nt < 2; ++nt){
      bf16x8 bb = *(const bf16x8*)(bext + (nt*16 + l15)*LDB2 + s*32 + quad*8);
      acc[nt] = __builtin_amdgcn_mfma_f32_16x16x32_bf16(aq, bb, acc[nt], 0, 0, 0);
    }
  }

  #pragma unroll
  for (int nt = 0; nt < 2; ++nt){
    #pragma unroll
    for (int reg = 0; reg < 4; ++reg){
      int o = wv*16 + quad*4 + reg;
      int p = nt*16 + l15;
      size_t idx = (((size_t)(b*HIDC + o))<<16) + n0 + p;
      float qpre = acc[nt][reg] + bq_out[o] + bf2f(qx_ws[idx]);
      float qf = tanhf_(qpre);
      float zf = bf2f(z_ws[idx]);
      float hv = h[idx];
      out[idx] = (1.f - zf)*hv + zf*qf;
    }
  }
}

extern "C" void kernel_launch(void* const* d_in, const int* in_sizes, int n_in,
                              void* d_out, int out_size, void* d_ws, size_t ws_size,
                              hipStream_t stream){
  const float* xyz    = (const float*)d_in[0];
  const float* h      = (const float*)d_in[1];
  const float* x      = (const float*)d_in[2];
  const int*   knn    = (const int*)d_in[3];
  const float* wz_pos = (const float*)d_in[4];
  const float* bz_pos = (const float*)d_in[5];
  const float* wz_out = (const float*)d_in[6];
  const float* bz_out = (const float*)d_in[7];
  const float* wr_pos = (const float*)d_in[8];
  const float* br_pos = (const float*)d_in[9];
  const float* wr_out = (const float*)d_in[10];
  const float* br_out = (const float*)d_in[11];
  const float* wq_pos = (const float*)d_in[12];
  const float* bq_pos = (const float*)d_in[13];
  const float* wq_out = (const float*)d_in[14];
  const float* bq_out = (const float*)d_in[15];
  float* out = (float*)d_out;

  // ws (u16): hxT[16777216] | rhT[8388608] | z[8388608] | qx[8388608] | A[114688]
  u16* ws    = (u16*)d_ws;
  u16* hxT   = ws;
  u16* rhT   = ws + 16777216;
  u16* z_ws  = ws + 25165824;
  u16* qx_ws = ws + 33554432;
  u16* A     = ws + 41943040;

  kprep<<<448, 256, 0, stream>>>(wz_out, wz_pos, bz_pos, wr_out, wr_pos, br_pos,
                                 wq_out, wq_pos, bq_pos, A);
  k_pack<<<2048, 256, 0, stream>>>(h, x, hxT);
  k_zr<<<8192, 256, 0, stream>>>(xyz, h, knn, bz_out, br_out, A, hxT, rhT, z_ws, qx_ws);
  k_q<<<4096, 256, 0, stream>>>(xyz, h, knn, bq_out, A + 98304, rhT, z_ws, qx_ws, out);
}

// Round 2
// 232.167 us; speedup vs baseline: 1.0993x; 1.0993x over previous
//
#include <hip/hip_runtime.h>

#define NPTS 65536
#define BATCH 2
#define CCH 128
#define HIDC 64
#define LDB 520      // k_zr bext row stride u16 (512+8 pad)
#define LDB2 264     // k_q bext row stride u16 (256+8 pad)
#define PLD 130      // k_pack tile row stride u16 (2 mod 4 -> 2-way banks on transpose writes)

typedef unsigned short u16;
typedef unsigned int u32;
typedef __bf16 bf16_t;
typedef bf16_t bf16x8 __attribute__((ext_vector_type(8)));
typedef float f32x4 __attribute__((ext_vector_type(4)));
typedef float f32x2 __attribute__((ext_vector_type(2)));

__device__ __forceinline__ u16 f2bf(float f){
  union { float f; unsigned u; } v; v.f = f;
  unsigned r = v.u + 0x7FFFu + ((v.u >> 16) & 1u);
  return (u16)(r >> 16);
}
__device__ __forceinline__ float bf2f(u16 u){
  union { unsigned u; float f; } v; v.u = ((unsigned)u) << 16; return v.f;
}
__device__ __forceinline__ u32 pkrn(float a, float b){
  union { float f; u32 u; } ua, ub; ua.f = a; ub.f = b;
  return ((ua.u + 0x8000u) >> 16) | ((ub.u + 0x8000u) & 0xffff0000u);
}
__device__ __forceinline__ float sigmoidf_(float v){ return 1.f/(1.f+__expf(-v)); }
__device__ __forceinline__ float tanhf_(float v){
  v = fminf(10.f, fmaxf(-10.f, v));
  float e = __expf(2.f*v);
  return (e-1.f)/(e+1.f);
}

// A matrices (bf16), fragment-permuted. First 98304: Az|Ar|Aq at K=512
// (phys k = s*32+quad*8+t; j=pk>>7, chunk=(pk>>3)&15, tt=pk&7;
//  orig=chunk*32+j*8+tt; c=orig>>2, m=orig&3). Then 16384: Aqrh at K=256
// (k2=s*32+quad*8+t; j=k2>>6, chunk=(k2>>3)&7; c in [0,64)).
__global__ __launch_bounds__(256) void kprep(
    const float* __restrict__ wz, const float* __restrict__ wzp, const float* __restrict__ bzp,
    const float* __restrict__ wr, const float* __restrict__ wrp, const float* __restrict__ brp,
    const float* __restrict__ wq, const float* __restrict__ wqp, const float* __restrict__ bqp,
    u16* __restrict__ A){
  int idx = blockIdx.x*256 + threadIdx.x;          // 0..114687
  if (idx < 98304){
    int t = idx & 7, o = (idx>>3)&63, quad = (idx>>9)&3, s = (idx>>11)&15, g = idx>>15;
    int pk = s*32 + quad*8 + t;
    int j = pk>>7, chunk = (pk>>3)&15, tt = pk&7;
    int orig = chunk*32 + j*8 + tt;
    int c = orig>>2, m = orig&3;
    const float* W  = (g==0)? wz  : (g==1)? wr  : wq;
    const float* wp = (g==0)? wzp : (g==1)? wrp : wqp;
    const float* bp = (g==0)? bzp : (g==1)? brp : bqp;
    float coef = m ? wp[c*3 + m - 1] : bp[c];
    A[idx] = f2bf(W[o*CCH + c] * coef);
  } else {
    int i2 = idx - 98304;
    int t = i2 & 7, o = (i2>>3)&63, quad = (i2>>9)&3, s = (i2>>11)&7;
    int k2 = s*32 + quad*8 + t;
    int j = k2>>6, chunk = (k2>>3)&7, tt = k2&7;
    int orig = chunk*32 + j*8 + tt;
    int c = orig>>2, m = orig&3;                   // c in [0,64): rh channels
    float coef = m ? wqp[c*3 + m - 1] : bqp[c];
    A[idx] = f2bf(wq[o*CCH + c] * coef);
  }
}

// Transpose h,x [B,64,N] fp32 -> hxT [B,N,128] bf16 rows.
__global__ __launch_bounds__(256) void k_pack(const float* __restrict__ h,
    const float* __restrict__ x, u16* __restrict__ hxT){
  __shared__ __align__(16) u16 tile[64*PLD];
  int tid = threadIdx.x;
  int b = blockIdx.x >> 10, n0 = (blockIdx.x & 1023) << 6;
  #pragma unroll
  for (int i = 0; i < 8; ++i){
    int cc = (tid>>4) + i*16;                      // 0..127
    int nn = (tid & 15)*4;
    const float* src = (cc < HIDC)
        ? (h + (((size_t)(b*HIDC + cc))<<16) + n0 + nn)
        : (x + (((size_t)(b*HIDC + cc - HIDC))<<16) + n0 + nn);
    float4 v = *(const float4*)src;
    tile[(nn+0)*PLD + cc] = f2bf(v.x);
    tile[(nn+1)*PLD + cc] = f2bf(v.y);
    tile[(nn+2)*PLD + cc] = f2bf(v.z);
    tile[(nn+3)*PLD + cc] = f2bf(v.w);
  }
  __syncthreads();
  #pragma unroll
  for (int i = 0; i < 4; ++i){
    int tsk = tid + (i<<8);                        // 0..1023: 64 n x 16 chunks
    int n = tsk>>4, ch = (tsk&15)*8;
    uint4 v = *(const uint4*)(tile + n*PLD + ch);
    *(uint4*)(hxT + (((size_t)(b<<16) + n0 + n)<<7) + ch) = v;
  }
}

// Moment accumulation on f32x2 (v_pk_fma_f32).
// m-arrays: index q_ = dword (channel pair); .x = even channel, .y = odd channel.
#define ACCUM(gv, rv) { \
  u32 dw_[4] = {gv.x, gv.y, gv.z, gv.w}; \
  _Pragma("unroll") \
  for (int q_ = 0; q_ < 4; ++q_){ \
    union { u32 u; float f; } lo_, hi_; \
    lo_.u = dw_[q_] << 16; hi_.u = dw_[q_] & 0xffff0000u; \
    f32x2 v_ = {lo_.f, hi_.f}; \
    m0[q_] += v_; mx[q_] += rv.x * v_; my[q_] += rv.y * v_; mz[q_] += rv.z * v_; \
  } }

#define PACKROW(row, CHOFF, STRIDE) { \
  _Pragma("unroll") \
  for (int j_ = 0; j_ < 4; ++j_){ \
    uint4 v_; \
    v_.x = pkrn(m0[j_].x, mx[j_].x); v_.y = pkrn(my[j_].x, mz[j_].x); \
    v_.z = pkrn(m0[j_].y, mx[j_].y); v_.w = pkrn(my[j_].y, mz[j_].y); \
    *(uint4*)((row) + j_*(STRIDE) + (CHOFF)) = v_; \
  } }

#define MOMGRP(PP, GA, GB, GC, GD) { \
  float4 r0 = relk[(PP)*4+0], r1 = relk[(PP)*4+1], r2 = relk[(PP)*4+2], r3 = relk[(PP)*4+3]; \
  f32x2 m0[4] = {{0,0},{0,0},{0,0},{0,0}}, mx[4] = {{0,0},{0,0},{0,0},{0,0}}; \
  f32x2 my[4] = {{0,0},{0,0},{0,0},{0,0}}, mz[4] = {{0,0},{0,0},{0,0},{0,0}}; \
  ACCUM(GA, r0); ACCUM(GB, r1); ACCUM(GC, r2); ACCUM(GD, r3); \
  PACKROW(bext + (PP)*LDB, chk*8, 128); }

// z & r gates + q-gate x-partial. 64 points/block (nt=4):
// halves A-matrix L2 traffic and per-point block overhead vs 32-pt config.
// LDS 71680 B -> 2 blocks/CU; 16 gather loads in flight per thread.
__global__ __launch_bounds__(256, 2) void k_zr(
    const float* __restrict__ xyz, const float* __restrict__ h,
    const int* __restrict__ knn,
    const float* __restrict__ bz_out, const float* __restrict__ br_out,
    const u16* __restrict__ Azr,    // Az at 0, Ar at +32768, Aq at +65536
    const u16* __restrict__ hxT, u16* __restrict__ rhT,
    u16* __restrict__ z_ws, u16* __restrict__ qx_ws)
{
  __shared__ __align__(16) u16 bext[64*LDB];       // 66560 B
  __shared__ __align__(16) float4 relk[256];
  __shared__ __align__(16) int4 jlds[64];

  int tid = threadIdx.x; int lane = tid & 63; int wv = tid >> 6;
  int b = blockIdx.x >> 10, n0 = (blockIdx.x & 1023) << 6;
  size_t bN = (size_t)b * NPTS;

  {
    int p = tid >> 2, k = tid & 3;
    int j = knn[((bN + n0 + p) << 2) + k];
    ((int*)jlds)[tid] = j;
    const float* xb = xyz + (size_t)b*3*NPTS;
    float cx = xb[n0+p], cy = xb[NPTS + n0+p], cz = xb[2*NPTS + n0+p];
    relk[tid] = make_float4(xb[j]-cx, xb[NPTS+j]-cy, xb[2*NPTS+j]-cz, 0.f);
  }
  __syncthreads();

  // gather: 4 tasks/thread (64 p x 16 chunks), all 16 loads issued up front
  const u16* hxTb = hxT + (bN << 7);
  int pA = tid >> 4, chk = tid & 15;
  const u16* cb = hxTb + chk*8;
  int4 j0 = jlds[pA], j1 = jlds[pA+16], j2 = jlds[pA+32], j3 = jlds[pA+48];
  uint4 g00 = *(const uint4*)(cb + (((size_t)j0.x)<<7));
  uint4 g01 = *(const uint4*)(cb + (((size_t)j0.y)<<7));
  uint4 g02 = *(const uint4*)(cb + (((size_t)j0.z)<<7));
  uint4 g03 = *(const uint4*)(cb + (((size_t)j0.w)<<7));
  uint4 g10 = *(const uint4*)(cb + (((size_t)j1.x)<<7));
  uint4 g11 = *(const uint4*)(cb + (((size_t)j1.y)<<7));
  uint4 g12 = *(const uint4*)(cb + (((size_t)j1.z)<<7));
  uint4 g13 = *(const uint4*)(cb + (((size_t)j1.w)<<7));
  uint4 g20 = *(const uint4*)(cb + (((size_t)j2.x)<<7));
  uint4 g21 = *(const uint4*)(cb + (((size_t)j2.y)<<7));
  uint4 g22 = *(const uint4*)(cb + (((size_t)j2.z)<<7));
  uint4 g23 = *(const uint4*)(cb + (((size_t)j2.w)<<7));
  uint4 g30 = *(const uint4*)(cb + (((size_t)j3.x)<<7));
  uint4 g31 = *(const uint4*)(cb + (((size_t)j3.y)<<7));
  uint4 g32 = *(const uint4*)(cb + (((size_t)j3.z)<<7));
  uint4 g33 = *(const uint4*)(cb + (((size_t)j3.w)<<7));
  MOMGRP(pA,      g00, g01, g02, g03);
  MOMGRP(pA + 16, g10, g11, g12, g13);
  MOMGRP(pA + 32, g20, g21, g22, g23);
  MOMGRP(pA + 48, g30, g31, g32, g33);
  __syncthreads();

  // MFMA: z,r over K=512; q x-part over the s&2 slices (c>=64). nt=4 tiles (64 pts).
  int l15 = lane & 15, quad = lane >> 4;
  int orow = wv*16 + l15;
  f32x4 accz[4], accr[4], accq[4];
  #pragma unroll
  for (int nt = 0; nt < 4; ++nt){
    accz[nt] = (f32x4){0,0,0,0}; accr[nt] = (f32x4){0,0,0,0}; accq[nt] = (f32x4){0,0,0,0};
  }
  #pragma unroll
  for (int s = 0; s < 16; ++s){
    bf16x8 az = *(const bf16x8*)(Azr + ((s*4 + quad)*64 + orow)*8);
    bf16x8 ar = *(const bf16x8*)(Azr + 32768 + ((s*4 + quad)*64 + orow)*8);
    if (s & 2){
      bf16x8 aq = *(const bf16x8*)(Azr + 65536 + ((s*4 + quad)*64 + orow)*8);
      #pragma unroll
      for (int nt = 0; nt < 4; ++nt){
        bf16x8 bb = *(const bf16x8*)(bext + (nt*16 + l15)*LDB + s*32 + quad*8);
        accz[nt] = __builtin_amdgcn_mfma_f32_16x16x32_bf16(az, bb, accz[nt], 0, 0, 0);
        accr[nt] = __builtin_amdgcn_mfma_f32_16x16x32_bf16(ar, bb, accr[nt], 0, 0, 0);
        accq[nt] = __builtin_amdgcn_mfma_f32_16x16x32_bf16(aq, bb, accq[nt], 0, 0, 0);
      }
    } else {
      #pragma unroll
      for (int nt = 0; nt < 4; ++nt){
        bf16x8 bb = *(const bf16x8*)(bext + (nt*16 + l15)*LDB + s*32 + quad*8);
        accz[nt] = __builtin_amdgcn_mfma_f32_16x16x32_bf16(az, bb, accz[nt], 0, 0, 0);
        accr[nt] = __builtin_amdgcn_mfma_f32_16x16x32_bf16(ar, bb, accr[nt], 0, 0, 0);
      }
    }
  }
  __syncthreads();   // bext reads done; reuse as staging

  u16* zst  = bext;                 // [64 o][72]
  u16* rhst = bext + 4608;          // [64 p][72]
  u16* qxst = bext + 9216;          // [64 o][72]
  #pragma unroll
  for (int nt = 0; nt < 4; ++nt){
    #pragma unroll
    for (int reg = 0; reg < 4; ++reg){
      int o = wv*16 + quad*4 + reg;               // C/D: row = quad*4+reg
      int p = nt*16 + l15;                        // col = lane&15
      float zf = sigmoidf_(accz[nt][reg] + bz_out[o]);
      float rf = sigmoidf_(accr[nt][reg] + br_out[o]);
      float hv = h[(((size_t)(b*HIDC + o))<<16) + n0 + p];
      zst[o*72 + p] = f2bf(zf);
      rhst[p*72 + o] = f2bf(rf * hv);
      qxst[o*72 + p] = f2bf(accq[nt][reg]);       // no bias (bq_out added in k_q)
    }
  }
  __syncthreads();

  #pragma unroll
  for (int i = 0; i < 2; ++i){
    int t = tid + (i<<8);
    int a = t >> 3, c8 = (t & 7)*8;               // a: point or o-row; c8: 8-elem chunk
    uint4 vr = *(const uint4*)(rhst + a*72 + c8);
    *(uint4*)(rhT + ((bN + n0 + a)<<6) + c8) = vr;
    uint4 vz = *(const uint4*)(zst + a*72 + c8);
    *(uint4*)(z_ws + (((size_t)(b*HIDC + a))<<16) + n0 + c8) = vz;
    uint4 vq = *(const uint4*)(qxst + a*72 + c8);
    *(uint4*)(qx_ws + (((size_t)(b*HIDC + a))<<16) + n0 + c8) = vq;
  }
}

// q gate (rh half via gather, x half from qx_ws) + final combine. 64 points/block.
__global__ __launch_bounds__(256, 4) void k_q(
    const float* __restrict__ xyz, const float* __restrict__ h,
    const int* __restrict__ knn,
    const float* __restrict__ bq_out,
    const u16* __restrict__ Aqrh,
    const u16* __restrict__ rhT, const u16* __restrict__ z_ws,
    const u16* __restrict__ qx_ws, float* __restrict__ out)
{
  __shared__ __align__(16) u16 bext[64*LDB2];      // 33792 B
  __shared__ __align__(16) float4 relk[256];
  __shared__ __align__(16) int4 jlds[64];

  int tid = threadIdx.x; int lane = tid & 63; int wv = tid >> 6;
  int b = blockIdx.x >> 10, n0 = (blockIdx.x & 1023) << 6;
  size_t bN = (size_t)b * NPTS;

  {
    int p = tid >> 2, k = tid & 3;
    int j = knn[((bN + n0 + p) << 2) + k];
    ((int*)jlds)[tid] = j;
    const float* xb = xyz + (size_t)b*3*NPTS;
    float cx = xb[n0+p], cy = xb[NPTS + n0+p], cz = xb[2*NPTS + n0+p];
    relk[tid] = make_float4(xb[j]-cx, xb[NPTS+j]-cy, xb[2*NPTS+j]-cz, 0.f);
  }
  __syncthreads();

  // gather rh rows (64 ch = 128 B): 2 tasks/thread, 8 loads in flight
  const u16* rhTb = rhT + (bN << 6);
  int pA = tid >> 3, chk = tid & 7;
  int pB = pA + 32;
  int4 jA = jlds[pA], jB = jlds[pB];
  const u16* cb = rhTb + chk*8;
  uint4 ga0 = *(const uint4*)(cb + (((size_t)jA.x)<<6));
  uint4 ga1 = *(const uint4*)(cb + (((size_t)jA.y)<<6));
  uint4 ga2 = *(const uint4*)(cb + (((size_t)jA.z)<<6));
  uint4 ga3 = *(const uint4*)(cb + (((size_t)jA.w)<<6));
  uint4 gb0 = *(const uint4*)(cb + (((size_t)jB.x)<<6));
  uint4 gb1 = *(const uint4*)(cb + (((size_t)jB.y)<<6));
  uint4 gb2 = *(const uint4*)(cb + (((size_t)jB.z)<<6));
  uint4 gb3 = *(const uint4*)(cb + (((size_t)jB.w)<<6));
  {
    float4 r0 = relk[pA*4+0], r1 = relk[pA*4+1], r2 = relk[pA*4+2], r3 = relk[pA*4+3];
    f32x2 m0[4] = {{0,0},{0,0},{0,0},{0,0}}, mx[4] = {{0,0},{0,0},{0,0},{0,0}};
    f32x2 my[4] = {{0,0},{0,0},{0,0},{0,0}}, mz[4] = {{0,0},{0,0},{0,0},{0,0}};
    ACCUM(ga0, r0); ACCUM(ga1, r1); ACCUM(ga2, r2); ACCUM(ga3, r3);
    PACKROW(bext + pA*LDB2, chk*8, 64);
  }
  {
    float4 r0 = relk[pB*4+0], r1 = relk[pB*4+1], r2 = relk[pB*4+2], r3 = relk[pB*4+3];
    f32x2 m0[4] = {{0,0},{0,0},{0,0},{0,0}}, mx[4] = {{0,0},{0,0},{0,0},{0,0}};
    f32x2 my[4] = {{0,0},{0,0},{0,0},{0,0}}, mz[4] = {{0,0},{0,0},{0,0},{0,0}};
    ACCUM(gb0, r0); ACCUM(gb1, r1); ACCUM(gb2, r2); ACCUM(gb3, r3);
    PACKROW(bext + pB*LDB2, chk*8, 64);
  }
  __syncthreads();

  int l15 = lane & 15, quad = lane >> 4;
  int orow = wv*16 + l15;
  f32x4 acc[4];
  #pragma unroll
  for (int nt = 0; nt < 4; ++nt) acc[nt] = (f32x4){0,0,0,0};
  #pragma unroll
  for (int s = 0; s < 8; ++s){
    bf16x8 aq = *(const bf16x8*)(Aqrh + ((s*4 + quad)*64 + orow)*8);
    #pragma unroll
    for (int nt = 0; nt < 4; ++nt){
      bf16x8 bb = *(const bf16x8*)(bext + (nt*16 + l15)*LDB2 + s*32 + quad*8);
      acc[nt] = __builtin_amdgcn_mfma_f32_16x16x32_bf16(aq, bb, acc[nt], 0, 0, 0);
    }
  }

  #pragma unroll
  for (int nt = 0; nt < 4; ++nt){
    #pragma unroll
    for (int reg = 0; reg < 4; ++reg){
      int o = wv*16 + quad*4 + reg;
      int p = nt*16 + l15;
      size_t idx = (((size_t)(b*HIDC + o))<<16) + n0 + p;
      float qpre = acc[nt][reg] + bq_out[o] + bf2f(qx_ws[idx]);
      float qf = tanhf_(qpre);
      float zf = bf2f(z_ws[idx]);
      float hv = h[idx];
      out[idx] = (1.f - zf)*hv + zf*qf;
    }
  }
}

extern "C" void kernel_launch(void* const* d_in, const int* in_sizes, int n_in,
                              void* d_out, int out_size, void* d_ws, size_t ws_size,
                              hipStream_t stream){
  const float* xyz    = (const float*)d_in[0];
  const float* h      = (const float*)d_in[1];
  const float* x      = (const float*)d_in[2];
  const int*   knn    = (const int*)d_in[3];
  const float* wz_pos = (const float*)d_in[4];
  const float* bz_pos = (const float*)d_in[5];
  const float* wz_out = (const float*)d_in[6];
  const float* bz_out = (const float*)d_in[7];
  const float* wr_pos = (const float*)d_in[8];
  const float* br_pos = (const float*)d_in[9];
  const float* wr_out = (const float*)d_in[10];
  const float* br_out = (const float*)d_in[11];
  const float* wq_pos = (const float*)d_in[12];
  const float* bq_pos = (const float*)d_in[13];
  const float* wq_out = (const float*)d_in[14];
  const float* bq_out = (const float*)d_in[15];
  float* out = (float*)d_out;

  // ws (u16): hxT[16777216] | rhT[8388608] | z[8388608] | qx[8388608] | A[114688]
  u16* ws    = (u16*)d_ws;
  u16* hxT   = ws;
  u16* rhT   = ws + 16777216;
  u16* z_ws  = ws + 25165824;
  u16* qx_ws = ws + 33554432;
  u16* A     = ws + 41943040;

  kprep<<<448, 256, 0, stream>>>(wz_out, wz_pos, bz_pos, wr_out, wr_pos, br_pos,
                                 wq_out, wq_pos, bq_pos, A);
  k_pack<<<2048, 256, 0, stream>>>(h, x, hxT);
  k_zr<<<2048, 256, 0, stream>>>(xyz, h, knn, bz_out, br_out, A, hxT, rhT, z_ws, qx_ws);
  k_q<<<2048, 256, 0, stream>>>(xyz, h, knn, bq_out, A + 98304, rhT, z_ws, qx_ws, out);
}

// Round 3
// 224.297 us; speedup vs baseline: 1.1378x; 1.0351x over previous
//
#include <hip/hip_runtime.h>

#define NPTS 65536
#define BATCH 2
#define CCH 128
#define HIDC 64
#define LDB 520      // k_zr bext row stride u16 (512+8 pad)
#define LDB2 264     // k_q bext row stride u16 (256+8 pad)
#define PLD 130      // k_pack tile row stride u16 (2 mod 4 -> 2-way banks on transpose writes)

typedef unsigned short u16;
typedef unsigned int u32;
typedef __bf16 bf16_t;
typedef bf16_t bf16x8 __attribute__((ext_vector_type(8)));
typedef float f32x4 __attribute__((ext_vector_type(4)));
typedef float f32x2 __attribute__((ext_vector_type(2)));

__device__ __forceinline__ u16 f2bf(float f){
  union { float f; unsigned u; } v; v.f = f;
  unsigned r = v.u + 0x7FFFu + ((v.u >> 16) & 1u);
  return (u16)(r >> 16);
}
__device__ __forceinline__ float bf2f(u16 u){
  union { unsigned u; float f; } v; v.u = ((unsigned)u) << 16; return v.f;
}
__device__ __forceinline__ u32 pkrn(float a, float b){
  union { float f; u32 u; } ua, ub; ua.f = a; ub.f = b;
  return ((ua.u + 0x8000u) >> 16) | ((ub.u + 0x8000u) & 0xffff0000u);
}
__device__ __forceinline__ float sigmoidf_(float v){ return 1.f/(1.f+__expf(-v)); }
__device__ __forceinline__ float tanhf_(float v){
  v = fminf(10.f, fmaxf(-10.f, v));
  float e = __expf(2.f*v);
  return (e-1.f)/(e+1.f);
}

// A matrices (bf16), fragment-permuted. First 98304: Az|Ar|Aq at K=512
// (phys k = s*32+quad*8+t; j=pk>>7, chunk=(pk>>3)&15, tt=pk&7;
//  orig=chunk*32+j*8+tt; c=orig>>2, m=orig&3). Then 16384: Aqrh at K=256
// (k2=s*32+quad*8+t; j=k2>>6, chunk=(k2>>3)&7; c in [0,64)).
__global__ __launch_bounds__(256) void kprep(
    const float* __restrict__ wz, const float* __restrict__ wzp, const float* __restrict__ bzp,
    const float* __restrict__ wr, const float* __restrict__ wrp, const float* __restrict__ brp,
    const float* __restrict__ wq, const float* __restrict__ wqp, const float* __restrict__ bqp,
    u16* __restrict__ A){
  int idx = blockIdx.x*256 + threadIdx.x;          // 0..114687
  if (idx < 98304){
    int t = idx & 7, o = (idx>>3)&63, quad = (idx>>9)&3, s = (idx>>11)&15, g = idx>>15;
    int pk = s*32 + quad*8 + t;
    int j = pk>>7, chunk = (pk>>3)&15, tt = pk&7;
    int orig = chunk*32 + j*8 + tt;
    int c = orig>>2, m = orig&3;
    const float* W  = (g==0)? wz  : (g==1)? wr  : wq;
    const float* wp = (g==0)? wzp : (g==1)? wrp : wqp;
    const float* bp = (g==0)? bzp : (g==1)? brp : bqp;
    float coef = m ? wp[c*3 + m - 1] : bp[c];
    A[idx] = f2bf(W[o*CCH + c] * coef);
  } else {
    int i2 = idx - 98304;
    int t = i2 & 7, o = (i2>>3)&63, quad = (i2>>9)&3, s = (i2>>11)&7;
    int k2 = s*32 + quad*8 + t;
    int j = k2>>6, chunk = (k2>>3)&7, tt = k2&7;
    int orig = chunk*32 + j*8 + tt;
    int c = orig>>2, m = orig&3;                   // c in [0,64): rh channels
    float coef = m ? wqp[c*3 + m - 1] : bqp[c];
    A[idx] = f2bf(wq[o*CCH + c] * coef);
  }
}

// Transpose h,x [B,64,N] fp32 -> hxT [B,N,128] bf16 rows.
__global__ __launch_bounds__(256) void k_pack(const float* __restrict__ h,
    const float* __restrict__ x, u16* __restrict__ hxT){
  __shared__ __align__(16) u16 tile[64*PLD];
  int tid = threadIdx.x;
  int b = blockIdx.x >> 10, n0 = (blockIdx.x & 1023) << 6;
  #pragma unroll
  for (int i = 0; i < 8; ++i){
    int cc = (tid>>4) + i*16;                      // 0..127
    int nn = (tid & 15)*4;
    const float* src = (cc < HIDC)
        ? (h + (((size_t)(b*HIDC + cc))<<16) + n0 + nn)
        : (x + (((size_t)(b*HIDC + cc - HIDC))<<16) + n0 + nn);
    float4 v = *(const float4*)src;
    tile[(nn+0)*PLD + cc] = f2bf(v.x);
    tile[(nn+1)*PLD + cc] = f2bf(v.y);
    tile[(nn+2)*PLD + cc] = f2bf(v.z);
    tile[(nn+3)*PLD + cc] = f2bf(v.w);
  }
  __syncthreads();
  #pragma unroll
  for (int i = 0; i < 4; ++i){
    int tsk = tid + (i<<8);                        // 0..1023: 64 n x 16 chunks
    int n = tsk>>4, ch = (tsk&15)*8;
    uint4 v = *(const uint4*)(tile + n*PLD + ch);
    *(uint4*)(hxT + (((size_t)(b<<16) + n0 + n)<<7) + ch) = v;
  }
}

// Moment accumulation on f32x2 (v_pk_fma_f32).
#define ACCUM(gv, rv) { \
  u32 dw_[4] = {gv.x, gv.y, gv.z, gv.w}; \
  _Pragma("unroll") \
  for (int q_ = 0; q_ < 4; ++q_){ \
    union { u32 u; float f; } lo_, hi_; \
    lo_.u = dw_[q_] << 16; hi_.u = dw_[q_] & 0xffff0000u; \
    f32x2 v_ = {lo_.f, hi_.f}; \
    m0[q_] += v_; mx[q_] += rv.x * v_; my[q_] += rv.y * v_; mz[q_] += rv.z * v_; \
  } }

#define PACKROW(row, CHOFF, STRIDE) { \
  _Pragma("unroll") \
  for (int j_ = 0; j_ < 4; ++j_){ \
    uint4 v_; \
    v_.x = pkrn(m0[j_].x, mx[j_].x); v_.y = pkrn(my[j_].x, mz[j_].x); \
    v_.z = pkrn(m0[j_].y, mx[j_].y); v_.w = pkrn(my[j_].y, mz[j_].y); \
    *(uint4*)((row) + j_*(STRIDE) + (CHOFF)) = v_; \
  } }

#define MFMA_BF16(A_, B_, C_) __builtin_amdgcn_mfma_f32_16x16x32_bf16(A_, B_, C_, 0, 0, 0)

// z & r gates + q-gate x-partial. 32 points/block, 4 blocks/CU (round-0 geometry).
// A-fragment double-buffer ring: groups of 4 s-slices loaded one group ahead.
__global__ __launch_bounds__(256, 4) void k_zr(
    const float* __restrict__ xyz, const float* __restrict__ h,
    const int* __restrict__ knn,
    const float* __restrict__ bz_out, const float* __restrict__ br_out,
    const u16* __restrict__ Azr,    // Az at 0, Ar at +32768, Aq at +65536
    const u16* __restrict__ hxT, u16* __restrict__ rhT,
    u16* __restrict__ z_ws, u16* __restrict__ qx_ws)
{
  __shared__ __align__(16) u16 bext[32*LDB];       // 33280 B
  __shared__ __align__(16) float4 relk[128];
  __shared__ __align__(16) int4 jlds[32];

  int tid = threadIdx.x; int lane = tid & 63; int wv = tid >> 6;
  int b = blockIdx.x >> 11, n0 = (blockIdx.x & 2047) << 5;
  size_t bN = (size_t)b * NPTS;

  if (tid < 128){
    int p = tid >> 2, k = tid & 3;
    int j = knn[((bN + n0 + p) << 2) + k];
    ((int*)jlds)[tid] = j;
    const float* xb = xyz + (size_t)b*3*NPTS;
    float cx = xb[n0+p], cy = xb[NPTS + n0+p], cz = xb[2*NPTS + n0+p];
    relk[tid] = make_float4(xb[j]-cx, xb[NPTS+j]-cy, xb[2*NPTS+j]-cz, 0.f);
  }
  __syncthreads();

  // gather: 2 tasks/thread, all 8 loads issued before any accumulation
  const u16* hxTb = hxT + (bN << 7);
  int pA = tid >> 4, chk = tid & 15;
  int pB = pA + 16;
  int4 jA = jlds[pA], jB = jlds[pB];
  const u16* cb = hxTb + chk*8;
  uint4 ga0 = *(const uint4*)(cb + (((size_t)jA.x)<<7));
  uint4 ga1 = *(const uint4*)(cb + (((size_t)jA.y)<<7));
  uint4 ga2 = *(const uint4*)(cb + (((size_t)jA.z)<<7));
  uint4 ga3 = *(const uint4*)(cb + (((size_t)jA.w)<<7));
  uint4 gb0 = *(const uint4*)(cb + (((size_t)jB.x)<<7));
  uint4 gb1 = *(const uint4*)(cb + (((size_t)jB.y)<<7));
  uint4 gb2 = *(const uint4*)(cb + (((size_t)jB.z)<<7));
  uint4 gb3 = *(const uint4*)(cb + (((size_t)jB.w)<<7));
  {
    float4 r0 = relk[pA*4+0], r1 = relk[pA*4+1], r2 = relk[pA*4+2], r3 = relk[pA*4+3];
    f32x2 m0[4] = {{0,0},{0,0},{0,0},{0,0}}, mx[4] = {{0,0},{0,0},{0,0},{0,0}};
    f32x2 my[4] = {{0,0},{0,0},{0,0},{0,0}}, mz[4] = {{0,0},{0,0},{0,0},{0,0}};
    ACCUM(ga0, r0); ACCUM(ga1, r1); ACCUM(ga2, r2); ACCUM(ga3, r3);
    PACKROW(bext + pA*LDB, chk*8, 128);
  }
  {
    float4 r0 = relk[pB*4+0], r1 = relk[pB*4+1], r2 = relk[pB*4+2], r3 = relk[pB*4+3];
    f32x2 m0[4] = {{0,0},{0,0},{0,0},{0,0}}, mx[4] = {{0,0},{0,0},{0,0},{0,0}};
    f32x2 my[4] = {{0,0},{0,0},{0,0},{0,0}}, mz[4] = {{0,0},{0,0},{0,0},{0,0}};
    ACCUM(gb0, r0); ACCUM(gb1, r1); ACCUM(gb2, r2); ACCUM(gb3, r3);
    PACKROW(bext + pB*LDB, chk*8, 128);
  }
  __syncthreads();

  // MFMA: z,r over K=512; q x-part over the s&2 slices (c>=64).
  // s-slices processed in 4 groups of 4, A-fragments double-buffered one group ahead.
  int l15 = lane & 15, quad = lane >> 4;
  int orow = wv*16 + l15;
  const u16* Abase = Azr + ((size_t)(quad*64 + orow))*8;   // + s*2048 walks s-slices

  f32x4 accz[2], accr[2], accq[2];
  #pragma unroll
  for (int nt = 0; nt < 2; ++nt){
    accz[nt] = (f32x4){0,0,0,0}; accr[nt] = (f32x4){0,0,0,0}; accq[nt] = (f32x4){0,0,0,0};
  }

  bf16x8 az0[4], ar0[4], aq0[2], az1[4], ar1[4], aq1[2];
  // per group SS: s = SS*4+j; aq needed for j=2,3 ((SS*4+j)&2 == j&2)
#define LOADA(AZ, AR, AQ, SS) { \
  _Pragma("unroll") \
  for (int j = 0; j < 4; ++j){ \
    AZ[j] = *(const bf16x8*)(Abase + ((SS)*4 + j)*2048); \
    AR[j] = *(const bf16x8*)(Abase + 32768 + ((SS)*4 + j)*2048); \
  } \
  AQ[0] = *(const bf16x8*)(Abase + 65536 + ((SS)*4 + 2)*2048); \
  AQ[1] = *(const bf16x8*)(Abase + 65536 + ((SS)*4 + 3)*2048); }

#define MFMAG(AZ, AR, AQ, SS) { \
  _Pragma("unroll") \
  for (int j = 0; j < 4; ++j){ \
    int s_ = (SS)*4 + j; \
    _Pragma("unroll") \
    for (int nt = 0; nt < 2; ++nt){ \
      bf16x8 bb = *(const bf16x8*)(bext + (nt*16 + l15)*LDB + s_*32 + quad*8); \
      accz[nt] = MFMA_BF16(AZ[j], bb, accz[nt]); \
      accr[nt] = MFMA_BF16(AR[j], bb, accr[nt]); \
      if (j >= 2) accq[nt] = MFMA_BF16(AQ[j-2], bb, accq[nt]); \
    } } }

  LOADA(az0, ar0, aq0, 0);
  LOADA(az1, ar1, aq1, 1);
  MFMAG(az0, ar0, aq0, 0);
  LOADA(az0, ar0, aq0, 2);
  MFMAG(az1, ar1, aq1, 1);
  LOADA(az1, ar1, aq1, 3);
  MFMAG(az0, ar0, aq0, 2);
  MFMAG(az1, ar1, aq1, 3);

  __syncthreads();   // bext reads done; reuse as staging

  u16* zst  = bext;                 // [64 o][40]
  u16* rhst = bext + 2560;          // [32 p][72]
  u16* qxst = bext + 2560 + 2304;   // [64 o][40]
  #pragma unroll
  for (int nt = 0; nt < 2; ++nt){
    #pragma unroll
    for (int reg = 0; reg < 4; ++reg){
      int o = wv*16 + quad*4 + reg;               // C/D: row = quad*4+reg
      int p = nt*16 + l15;                        // col = lane&15
      float zf = sigmoidf_(accz[nt][reg] + bz_out[o]);
      float rf = sigmoidf_(accr[nt][reg] + br_out[o]);
      float hv = h[(((size_t)(b*HIDC + o))<<16) + n0 + p];
      zst[o*40 + p] = f2bf(zf);
      rhst[p*72 + o] = f2bf(rf * hv);
      qxst[o*40 + p] = f2bf(accq[nt][reg]);       // no bias (bq_out added in k_q)
    }
  }
  __syncthreads();

  { // rhT: 32 p x 64 ch = 256 uint4, one per thread
    int p = tid >> 3, ch = (tid & 7)*8;
    uint4 v = *(const uint4*)(rhst + p*72 + ch);
    *(uint4*)(rhT + ((bN + n0 + p)<<6) + ch) = v;
  }
  { // z: 64 o x 32 p = 256 uint4
    int o = tid >> 2, pc = (tid & 3)*8;
    uint4 v = *(const uint4*)(zst + o*40 + pc);
    *(uint4*)(z_ws + (((size_t)(b*HIDC + o))<<16) + n0 + pc) = v;
  }
  { // qx: 64 o x 32 p = 256 uint4
    int o = tid >> 2, pc = (tid & 3)*8;
    uint4 v = *(const uint4*)(qxst + o*40 + pc);
    *(uint4*)(qx_ws + (((size_t)(b*HIDC + o))<<16) + n0 + pc) = v;
  }
}

// q gate (rh half via gather, x half from qx_ws) + final combine. 64 points/block.
__global__ __launch_bounds__(256, 4) void k_q(
    const float* __restrict__ xyz, const float* __restrict__ h,
    const int* __restrict__ knn,
    const float* __restrict__ bq_out,
    const u16* __restrict__ Aqrh,
    const u16* __restrict__ rhT, const u16* __restrict__ z_ws,
    const u16* __restrict__ qx_ws, float* __restrict__ out)
{
  __shared__ __align__(16) u16 bext[64*LDB2];      // 33792 B
  __shared__ __align__(16) float4 relk[256];
  __shared__ __align__(16) int4 jlds[64];

  int tid = threadIdx.x; int lane = tid & 63; int wv = tid >> 6;
  int b = blockIdx.x >> 10, n0 = (blockIdx.x & 1023) << 6;
  size_t bN = (size_t)b * NPTS;

  {
    int p = tid >> 2, k = tid & 3;
    int j = knn[((bN + n0 + p) << 2) + k];
    ((int*)jlds)[tid] = j;
    const float* xb = xyz + (size_t)b*3*NPTS;
    float cx = xb[n0+p], cy = xb[NPTS + n0+p], cz = xb[2*NPTS + n0+p];
    relk[tid] = make_float4(xb[j]-cx, xb[NPTS+j]-cy, xb[2*NPTS+j]-cz, 0.f);
  }
  __syncthreads();

  // gather rh rows (64 ch = 128 B): 2 tasks/thread, 8 loads in flight
  const u16* rhTb = rhT + (bN << 6);
  int pA = tid >> 3, chk = tid & 7;
  int pB = pA + 32;
  int4 jA = jlds[pA], jB = jlds[pB];
  const u16* cb = rhTb + chk*8;
  uint4 ga0 = *(const uint4*)(cb + (((size_t)jA.x)<<6));
  uint4 ga1 = *(const uint4*)(cb + (((size_t)jA.y)<<6));
  uint4 ga2 = *(const uint4*)(cb + (((size_t)jA.z)<<6));
  uint4 ga3 = *(const uint4*)(cb + (((size_t)jA.w)<<6));
  uint4 gb0 = *(const uint4*)(cb + (((size_t)jB.x)<<6));
  uint4 gb1 = *(const uint4*)(cb + (((size_t)jB.y)<<6));
  uint4 gb2 = *(const uint4*)(cb + (((size_t)jB.z)<<6));
  uint4 gb3 = *(const uint4*)(cb + (((size_t)jB.w)<<6));
  {
    float4 r0 = relk[pA*4+0], r1 = relk[pA*4+1], r2 = relk[pA*4+2], r3 = relk[pA*4+3];
    f32x2 m0[4] = {{0,0},{0,0},{0,0},{0,0}}, mx[4] = {{0,0},{0,0},{0,0},{0,0}};
    f32x2 my[4] = {{0,0},{0,0},{0,0},{0,0}}, mz[4] = {{0,0},{0,0},{0,0},{0,0}};
    ACCUM(ga0, r0); ACCUM(ga1, r1); ACCUM(ga2, r2); ACCUM(ga3, r3);
    PACKROW(bext + pA*LDB2, chk*8, 64);
  }
  {
    float4 r0 = relk[pB*4+0], r1 = relk[pB*4+1], r2 = relk[pB*4+2], r3 = relk[pB*4+3];
    f32x2 m0[4] = {{0,0},{0,0},{0,0},{0,0}}, mx[4] = {{0,0},{0,0},{0,0},{0,0}};
    f32x2 my[4] = {{0,0},{0,0},{0,0},{0,0}}, mz[4] = {{0,0},{0,0},{0,0},{0,0}};
    ACCUM(gb0, r0); ACCUM(gb1, r1); ACCUM(gb2, r2); ACCUM(gb3, r3);
    PACKROW(bext + pB*LDB2, chk*8, 64);
  }
  __syncthreads();

  int l15 = lane & 15, quad = lane >> 4;
  int orow = wv*16 + l15;
  const u16* Abase = Aqrh + ((size_t)(quad*64 + orow))*8;  // + s*2048 walks s-slices
  f32x4 acc[4];
  #pragma unroll
  for (int nt = 0; nt < 4; ++nt) acc[nt] = (f32x4){0,0,0,0};

  bf16x8 a0[4], a1[4];
#define LOADAQ(AQ, SS) { \
  _Pragma("unroll") \
  for (int j = 0; j < 4; ++j) AQ[j] = *(const bf16x8*)(Abase + ((SS)*4 + j)*2048); }

#define MFMAGQ(AQ, SS) { \
  _Pragma("unroll") \
  for (int j = 0; j < 4; ++j){ \
    int s_ = (SS)*4 + j; \
    _Pragma("unroll") \
    for (int nt = 0; nt < 4; ++nt){ \
      bf16x8 bb = *(const bf16x8*)(bext + (nt*16 + l15)*LDB2 + s_*32 + quad*8); \
      acc[nt] = MFMA_BF16(AQ[j], bb, acc[nt]); \
    } } }

  LOADAQ(a0, 0);
  LOADAQ(a1, 1);
  MFMAGQ(a0, 0);
  MFMAGQ(a1, 1);

  #pragma unroll
  for (int nt = 0; nt < 4; ++nt){
    #pragma unroll
    for (int reg = 0; reg < 4; ++reg){
      int o = wv*16 + quad*4 + reg;
      int p = nt*16 + l15;
      size_t idx = (((size_t)(b*HIDC + o))<<16) + n0 + p;
      float qpre = acc[nt][reg] + bq_out[o] + bf2f(qx_ws[idx]);
      float qf = tanhf_(qpre);
      float zf = bf2f(z_ws[idx]);
      float hv = h[idx];
      out[idx] = (1.f - zf)*hv + zf*qf;
    }
  }
}

extern "C" void kernel_launch(void* const* d_in, const int* in_sizes, int n_in,
                              void* d_out, int out_size, void* d_ws, size_t ws_size,
                              hipStream_t stream){
  const float* xyz    = (const float*)d_in[0];
  const float* h      = (const float*)d_in[1];
  const float* x      = (const float*)d_in[2];
  const int*   knn    = (const int*)d_in[3];
  const float* wz_pos = (const float*)d_in[4];
  const float* bz_pos = (const float*)d_in[5];
  const float* wz_out = (const float*)d_in[6];
  const float* bz_out = (const float*)d_in[7];
  const float* wr_pos = (const float*)d_in[8];
  const float* br_pos = (const float*)d_in[9];
  const float* wr_out = (const float*)d_in[10];
  const float* br_out = (const float*)d_in[11];
  const float* wq_pos = (const float*)d_in[12];
  const float* bq_pos = (const float*)d_in[13];
  const float* wq_out = (const float*)d_in[14];
  const float* bq_out = (const float*)d_in[15];
  float* out = (float*)d_out;

  // ws (u16): hxT[16777216] | rhT[8388608] | z[8388608] | qx[8388608] | A[114688]
  u16* ws    = (u16*)d_ws;
  u16* hxT   = ws;
  u16* rhT   = ws + 16777216;
  u16* z_ws  = ws + 25165824;
  u16* qx_ws = ws + 33554432;
  u16* A     = ws + 41943040;

  kprep<<<448, 256, 0, stream>>>(wz_out, wz_pos, bz_pos, wr_out, wr_pos, br_pos,
                                 wq_out, wq_pos, bq_pos, A);
  k_pack<<<2048, 256, 0, stream>>>(h, x, hxT);
  k_zr<<<4096, 256, 0, stream>>>(xyz, h, knn, bz_out, br_out, A, hxT, rhT, z_ws, qx_ws);
  k_q<<<2048, 256, 0, stream>>>(xyz, h, knn, bq_out, A + 98304, rhT, z_ws, qx_ws, out);
}